// Round 5
// baseline (166.919 us; speedup 1.0000x reference)
//
#include <hip/hip_runtime.h>

#define BATCH 131072
#define XDIM 260          // 256 state + 4 goal
#define SDIM 256
#define HID 256
#define HHID 128
#define ODIM 128

typedef __attribute__((ext_vector_type(8))) short short8;   // bf16 x8 MFMA frag
typedef __attribute__((ext_vector_type(4))) float floatx4;  // MFMA accum

// fp32 -> bf16 round-to-nearest-even (finite inputs)
__device__ __forceinline__ short f2b(float f) {
    unsigned u = __float_as_uint(f);
    unsigned r = u + 0x7FFFu + ((u >> 16) & 1u);
    return (short)(r >> 16);
}

// ---------------------------------------------------------------------------
// prep: W0T[n][k]=bf16(W0[k][n]) (256x256), W1T[g][n][k] (4x128x256),
//       W2T[g][n][k] (4x128x128); zero bucket cursors.  (R2-proven, unchanged)
// ---------------------------------------------------------------------------
__global__ void prep_kernel(const float* __restrict__ W0, const float* __restrict__ W1,
                            const float* __restrict__ W2, short* __restrict__ W0T,
                            short* __restrict__ W1T, short* __restrict__ W2T,
                            int* __restrict__ cursor) {
    int i = blockIdx.x * 256 + threadIdx.x;   // grid 512*256 = 131072
    if (i < 4) cursor[i] = 0;
    if (i < 65536) {            // W0T
        int n = i >> 8, k = i & 255;
        W0T[i] = f2b(W0[k * HID + n]);
    }
    if (i < 131072) {           // W1T
        int g = i >> 15, r = i & 32767;
        int n = r >> 8, k = r & 255;
        W1T[i] = f2b(W1[(g * SDIM + k) * HHID + n]);
    }
    if (i < 65536) {            // W2T
        int g = i >> 14, r = i & 16383;
        int n = r >> 7, k = r & 127;
        W2T[i] = f2b(W2[(g * HHID + k) * ODIM + n]);
    }
}

// ---------------------------------------------------------------------------
// xcvt: x(state) fp32 -> XB bf16 (XB aliases d_out; fully overwrites it).
// Pure streaming, high-TLP: this is where the 134 MB fp32 read now lives,
// instead of inside the latency-bound GEMM-tile kernel.
// Numerics: f2b(x) — identical bits to R2's in-kernel staging.
// ---------------------------------------------------------------------------
__global__ void xcvt_kernel(const float* __restrict__ x, short* __restrict__ XB) {
    const int tid = threadIdx.x;
    const int r = tid >> 5;          // 0..7
    const int ch = tid & 31;         // 0..31, 8 floats each
    const int base = blockIdx.x * 64;
    #pragma unroll
    for (int i = 0; i < 8; ++i) {
        int row = base + i * 8 + r;
        const float* xr = x + (size_t)row * XDIM + ch * 8;
        float4 a = *reinterpret_cast<const float4*>(xr);
        float4 b = *reinterpret_cast<const float4*>(xr + 4);
        short8 s;
        s[0] = f2b(a.x); s[1] = f2b(a.y); s[2] = f2b(a.z); s[3] = f2b(a.w);
        s[4] = f2b(b.x); s[5] = f2b(b.y); s[6] = f2b(b.z); s[7] = f2b(b.w);
        *reinterpret_cast<short8*>(XB + (size_t)row * HID + ch * 8) = s;
    }
}

// ---------------------------------------------------------------------------
// bucket: per-row argmax(goal) -> counting sort (hierarchical; ~6us, R2-proven)
// ---------------------------------------------------------------------------
__global__ void bucket_kernel(const float* __restrict__ x, int* __restrict__ cursor,
                              int* __restrict__ perm) {
    __shared__ int lhist[4];
    __shared__ int lbase[4];
    const int tid = threadIdx.x;
    if (tid < 4) lhist[tid] = 0;
    __syncthreads();

    const int row = blockIdx.x * 256 + tid;
    const float4 gv = *reinterpret_cast<const float4*>(x + (size_t)row * XDIM + SDIM);
    int gi = 0; float best = gv.x;
    if (gv.y > best) { best = gv.y; gi = 1; }   // strict > keeps first max (jnp.argmax)
    if (gv.z > best) { best = gv.z; gi = 2; }
    if (gv.w > best) { best = gv.w; gi = 3; }

    const int lpos = atomicAdd(&lhist[gi], 1);
    __syncthreads();
    if (tid < 4) lbase[tid] = atomicAdd(&cursor[tid], lhist[tid]);
    __syncthreads();
    perm[gi * BATCH + lbase[gi] + lpos] = row;
}

// ---------------------------------------------------------------------------
// K1b: h = LeakyReLU(LN(XB @ W0 + b0)) -> bf16 H, written IN PLACE over the
// same d_out rows (each row owned by exactly one block -> race-free).
// Staging is now k2's proven bf16 gather (sequential rows); GEMM/LN/store
// are byte-for-byte R2 k1.
// ---------------------------------------------------------------------------
__global__ __launch_bounds__(256, 2) void k1b_gemm_ln(
        const short* XB, const float* __restrict__ b0,
        const float* __restrict__ gamma, const float* __restrict__ beta,
        const short* __restrict__ W0T, short* H) {
    __shared__ __align__(16) short a_lds[64][264];   // 256 + 8 pad
    __shared__ float psum[64][4];
    __shared__ float psq[64][4];
    __shared__ float mu_s[64];
    __shared__ float rs_s[64];

    const int tid = threadIdx.x;
    const int lane = tid & 63;
    const int w = tid >> 6;
    const int m0 = blockIdx.x * 64;

    // ---- stage bf16 rows -> LDS, 16B/lane coalesced (same loop as k2 gather)
    #pragma unroll
    for (int c = 0; c < 8; ++c) {
        int s = c * 256 + tid;                 // short8 slot, 64 rows x 32 slots
        int row = s >> 5;
        int k8 = (s & 31) << 3;
        short8 v = *reinterpret_cast<const short8*>(XB + (size_t)(m0 + row) * HID + k8);
        *reinterpret_cast<short8*>(&a_lds[row][k8]) = v;
    }
    __syncthreads();

    const int q = lane >> 4;
    const int l15 = lane & 15;

    floatx4 acc[4][4] = {};                    // [mi][ni], rows mi*16+q*4+r, cols w*64+ni*16+l15
    const short* Bw = W0T + (size_t)(w << 6) * HID;

    for (int k0 = 0; k0 < 256; k0 += 32) {
        short8 af[4], bf[4];
        #pragma unroll
        for (int mi = 0; mi < 4; ++mi)
            af[mi] = *reinterpret_cast<const short8*>(&a_lds[mi * 16 + l15][k0 + q * 8]);
        #pragma unroll
        for (int ni = 0; ni < 4; ++ni)
            bf[ni] = *reinterpret_cast<const short8*>(Bw + (size_t)(ni * 16 + l15) * HID + k0 + q * 8);
        #pragma unroll
        for (int mi = 0; mi < 4; ++mi)
            #pragma unroll
            for (int ni = 0; ni < 4; ++ni)
                acc[mi][ni] = __builtin_amdgcn_mfma_f32_16x16x32_bf16(af[mi], bf[ni], acc[mi][ni], 0, 0, 0);
    }

    // ---- + b0, LN stats (shfl_xor over the 16 lanes sharing a row, then LDS cross-wave)
    float bias[4], gm[4], bt[4];
    #pragma unroll
    for (int ni = 0; ni < 4; ++ni) {
        int col = (w << 6) + ni * 16 + l15;
        bias[ni] = b0[col]; gm[ni] = gamma[col]; bt[ni] = beta[col];
    }
    #pragma unroll
    for (int mi = 0; mi < 4; ++mi) {
        #pragma unroll
        for (int r = 0; r < 4; ++r) {
            float s = 0.f, ss = 0.f;
            #pragma unroll
            for (int ni = 0; ni < 4; ++ni) {
                float v = acc[mi][ni][r] + bias[ni];
                acc[mi][ni][r] = v;
                s += v; ss += v * v;
            }
            #pragma unroll
            for (int off = 1; off < 16; off <<= 1) {
                s  += __shfl_xor(s,  off, 64);
                ss += __shfl_xor(ss, off, 64);
            }
            if (l15 == 0) {
                int row = mi * 16 + q * 4 + r;
                psum[row][w] = s;
                psq[row][w]  = ss;
            }
        }
    }
    __syncthreads();
    if (tid < 64) {
        float s  = psum[tid][0] + psum[tid][1] + psum[tid][2] + psum[tid][3];
        float ss = psq[tid][0]  + psq[tid][1]  + psq[tid][2]  + psq[tid][3];
        float mu = s * (1.f / 256.f);
        float var = ss * (1.f / 256.f) - mu * mu;
        mu_s[tid] = mu;
        rs_s[tid] = rsqrtf(var + 1e-5f);
    }
    __syncthreads();

    // ---- normalize + leaky + store bf16 (in place over this block's XB rows)
    #pragma unroll
    for (int mi = 0; mi < 4; ++mi) {
        #pragma unroll
        for (int r = 0; r < 4; ++r) {
            int row = mi * 16 + q * 4 + r;
            float mu = mu_s[row], rs = rs_s[row];
            short* dst = H + (size_t)(m0 + row) * HID + (w << 6) + l15;
            #pragma unroll
            for (int ni = 0; ni < 4; ++ni) {
                float v = (acc[mi][ni][r] - mu) * rs * gm[ni] + bt[ni];
                v = (v >= 0.f) ? v : 0.1f * v;
                dst[ni * 16] = f2b(v);
            }
        }
    }
}

// ---------------------------------------------------------------------------
// K2: per (goal g, 64-row tile): t = relu(h @ W1[g] + b1[g]); out = t @ W2[g] + b2[g]
// H aliases out row-in-place (R2-proven race-free).  (unchanged)
// ---------------------------------------------------------------------------
__global__ __launch_bounds__(256, 2) void k2_heads(
        const short* H, const short* __restrict__ W1T, const short* __restrict__ W2T,
        const float* __restrict__ b1, const float* __restrict__ b2,
        const int* __restrict__ cursor, const int* __restrict__ perm,
        float* out) {
    const int g = blockIdx.y;
    const int t = blockIdx.x;
    const int cnt = cursor[g];
    if (t * 64 >= cnt) return;

    __shared__ __align__(16) short a_lds[64][264];
    __shared__ __align__(16) short t_lds[64][136];
    __shared__ int rows_s[64];

    const int tid = threadIdx.x;
    const int lane = tid & 63;
    const int w = tid >> 6;
    const int* pg = perm + (size_t)g * BATCH;

    if (tid < 64) {
        int idx = t * 64 + tid;
        rows_s[tid] = pg[idx < cnt ? idx : cnt - 1];
    }
    __syncthreads();

    // ---- gather h rows (bf16), coalesced 16B/lane
    #pragma unroll
    for (int c = 0; c < 8; ++c) {
        int s = c * 256 + tid;                 // short8 slot, 64 rows x 32 slots
        int row = s >> 5;
        int k8 = (s & 31) << 3;
        short8 v = *reinterpret_cast<const short8*>(H + (size_t)rows_s[row] * HID + k8);
        *reinterpret_cast<short8*>(&a_lds[row][k8]) = v;
    }
    __syncthreads();

    const int q = lane >> 4;
    const int l15 = lane & 15;

    // ---- GEMM1: 64x128, K=256; wave w owns cols [w*32, w*32+32)
    floatx4 acc1[4][2] = {};
    const short* B1 = W1T + (size_t)(g * HHID + (w << 5)) * HID;
    for (int k0 = 0; k0 < 256; k0 += 32) {
        short8 af[4], bf[2];
        #pragma unroll
        for (int mi = 0; mi < 4; ++mi)
            af[mi] = *reinterpret_cast<const short8*>(&a_lds[mi * 16 + l15][k0 + q * 8]);
        #pragma unroll
        for (int ni = 0; ni < 2; ++ni)
            bf[ni] = *reinterpret_cast<const short8*>(B1 + (size_t)(ni * 16 + l15) * HID + k0 + q * 8);
        #pragma unroll
        for (int mi = 0; mi < 4; ++mi)
            #pragma unroll
            for (int ni = 0; ni < 2; ++ni)
                acc1[mi][ni] = __builtin_amdgcn_mfma_f32_16x16x32_bf16(af[mi], bf[ni], acc1[mi][ni], 0, 0, 0);
    }
    // bias + relu -> t_lds (bf16)
    #pragma unroll
    for (int ni = 0; ni < 2; ++ni) {
        int col = (w << 5) + ni * 16 + l15;
        float bb = b1[g * HHID + col];
        #pragma unroll
        for (int mi = 0; mi < 4; ++mi)
            #pragma unroll
            for (int r = 0; r < 4; ++r) {
                int row = mi * 16 + q * 4 + r;
                float v = acc1[mi][ni][r] + bb;
                t_lds[row][col] = f2b(v > 0.f ? v : 0.f);
            }
    }
    __syncthreads();

    // ---- GEMM2: 64x128, K=128
    floatx4 acc2[4][2] = {};
    const short* B2 = W2T + (size_t)(g * ODIM + (w << 5)) * HHID;
    for (int k0 = 0; k0 < 128; k0 += 32) {
        short8 af[4], bf[2];
        #pragma unroll
        for (int mi = 0; mi < 4; ++mi)
            af[mi] = *reinterpret_cast<const short8*>(&t_lds[mi * 16 + l15][k0 + q * 8]);
        #pragma unroll
        for (int ni = 0; ni < 2; ++ni)
            bf[ni] = *reinterpret_cast<const short8*>(B2 + (size_t)(ni * 16 + l15) * HHID + k0 + q * 8);
        #pragma unroll
        for (int mi = 0; mi < 4; ++mi)
            #pragma unroll
            for (int ni = 0; ni < 2; ++ni)
                acc2[mi][ni] = __builtin_amdgcn_mfma_f32_16x16x32_bf16(af[mi], bf[ni], acc2[mi][ni], 0, 0, 0);
    }
    // bias + scatter out (fp32)
    #pragma unroll
    for (int ni = 0; ni < 2; ++ni) {
        int col = (w << 5) + ni * 16 + l15;
        float bb = b2[g * ODIM + col];
        #pragma unroll
        for (int mi = 0; mi < 4; ++mi)
            #pragma unroll
            for (int r = 0; r < 4; ++r) {
                int row = mi * 16 + q * 4 + r;
                int idx = t * 64 + row;
                if (idx < cnt)
                    out[(size_t)rows_s[row] * ODIM + col] = acc2[mi][ni][r] + bb;
            }
    }
}

// ---------------------------------------------------------------------------
// workspace layout (2.62 MB):
//   [0, 131072)            W0T bf16
//   [131072, 393216)       W1T bf16
//   [393216, 524288)       W2T bf16
//   [524288, 524304)       cursor (padded to 1024)
//   [525312, 2622464)      perm (4 x 131072 int)
// d_out pipeline (row-in-place at every step, one owner block per row):
//   xcvt: x -> XB(bf16) | k1b: XB -> H(bf16) | k2: H -> out(fp32)
// ---------------------------------------------------------------------------
extern "C" void kernel_launch(void* const* d_in, const int* in_sizes, int n_in,
                              void* d_out, int out_size, void* d_ws, size_t ws_size,
                              hipStream_t stream) {
    const float* x     = (const float*)d_in[0];
    const float* W0    = (const float*)d_in[1];
    const float* b0    = (const float*)d_in[2];
    const float* gamma = (const float*)d_in[3];
    const float* beta  = (const float*)d_in[4];
    const float* W1    = (const float*)d_in[5];
    const float* b1    = (const float*)d_in[6];
    const float* W2    = (const float*)d_in[7];
    const float* b2    = (const float*)d_in[8];

    char* ws = (char*)d_ws;
    short* W0T  = (short*)(ws);
    short* W1T  = (short*)(ws + 131072);
    short* W2T  = (short*)(ws + 393216);
    int* cursor = (int*)(ws + 524288);
    int* perm   = (int*)(ws + 525312);
    short* XB   = (short*)d_out;           // bf16 x-state, then h, then fp32 out
    float* out  = (float*)d_out;

    prep_kernel<<<512, 256, 0, stream>>>(W0, W1, W2, W0T, W1T, W2T, cursor);
    xcvt_kernel<<<BATCH / 64, 256, 0, stream>>>(x, XB);
    bucket_kernel<<<512, 256, 0, stream>>>(x, cursor, perm);
    k1b_gemm_ln<<<BATCH / 64, 256, 0, stream>>>(XB, b0, gamma, beta, W0T, XB);
    k2_heads<<<dim3(BATCH / 64, 4), 256, 0, stream>>>(XB, W1T, W2T, b1, b2, cursor, perm, out);
}

// Round 7
// 132.613 us; speedup vs baseline: 1.2587x; 1.2587x over previous
//
#include <hip/hip_runtime.h>

#define BATCH 131072
#define XDIM 260          // 256 state + 4 goal
#define SDIM 256
#define HID 256
#define HHID 128
#define ODIM 128

typedef __attribute__((ext_vector_type(8))) short short8;   // bf16 x8 MFMA frag
typedef __attribute__((ext_vector_type(4))) short short4v;
typedef __attribute__((ext_vector_type(4))) float floatx4;  // MFMA accum

// fp32 -> bf16 round-to-nearest-even (finite inputs)
__device__ __forceinline__ short f2b(float f) {
    unsigned u = __float_as_uint(f);
    unsigned r = u + 0x7FFFu + ((u >> 16) & 1u);
    return (short)(r >> 16);
}

// ---------------------------------------------------------------------------
// prep: W0T[n][k]=bf16(W0[k][n]) (256x256), W1T[g][n][k] (4x128x256),
//       W2T[g][n][k] (4x128x128); zero bucket cursors.  (R2-proven, unchanged)
// ---------------------------------------------------------------------------
__global__ void prep_kernel(const float* __restrict__ W0, const float* __restrict__ W1,
                            const float* __restrict__ W2, short* __restrict__ W0T,
                            short* __restrict__ W1T, short* __restrict__ W2T,
                            int* __restrict__ cursor) {
    int i = blockIdx.x * 256 + threadIdx.x;   // grid 512*256 = 131072
    if (i < 4) cursor[i] = 0;
    if (i < 65536) {            // W0T
        int n = i >> 8, k = i & 255;
        W0T[i] = f2b(W0[k * HID + n]);
    }
    if (i < 131072) {           // W1T
        int g = i >> 15, r = i & 32767;
        int n = r >> 8, k = r & 255;
        W1T[i] = f2b(W1[(g * SDIM + k) * HHID + n]);
    }
    if (i < 65536) {            // W2T
        int g = i >> 14, r = i & 16383;
        int n = r >> 7, k = r & 127;
        W2T[i] = f2b(W2[(g * HHID + k) * ODIM + n]);
    }
}

// ---------------------------------------------------------------------------
// bucket: per-row argmax(goal) -> counting sort (hierarchical; R2-proven)
// ---------------------------------------------------------------------------
__global__ void bucket_kernel(const float* __restrict__ x, int* __restrict__ cursor,
                              int* __restrict__ perm) {
    __shared__ int lhist[4];
    __shared__ int lbase[4];
    const int tid = threadIdx.x;
    if (tid < 4) lhist[tid] = 0;
    __syncthreads();

    const int row = blockIdx.x * 256 + tid;
    const float4 gv = *reinterpret_cast<const float4*>(x + (size_t)row * XDIM + SDIM);
    int gi = 0; float best = gv.x;
    if (gv.y > best) { best = gv.y; gi = 1; }   // strict > keeps first max (jnp.argmax)
    if (gv.z > best) { best = gv.z; gi = 2; }
    if (gv.w > best) { best = gv.w; gi = 3; }

    const int lpos = atomicAdd(&lhist[gi], 1);
    __syncthreads();
    if (tid < 4) lbase[tid] = atomicAdd(&cursor[tid], lhist[tid]);
    __syncthreads();
    perm[gi * BATCH + lbase[gi] + lpos] = row;
}

// ---------------------------------------------------------------------------
// K1: h = LeakyReLU(LN(state @ W0 + b0)) -> bf16, stored into H (aliases d_out)
// EXACTLY R4's kernel (absmax 9.765625e-4 proven) with ONE delta: a
// sched_barrier(0) between the 8-load batch and the convert/ds_write batch.
// R4's VGPR=68 proved the compiler sank each load to its use (2-deep
// pipeline -> 1.2 TB/s latency crawl); the fence forces 8 loads in flight
// (8KB/wave >> the ~9KB/CU needed to cover HBM latency at our share of BW).
// Staging is integer-only (no FMA-contraction freedom) and all arithmetic
// code below is untouched -> output bits identical to R4.
// ---------------------------------------------------------------------------
__global__ __launch_bounds__(256, 2) void k1_gemm_ln(
        const float* __restrict__ x, const float* __restrict__ b0,
        const float* __restrict__ gamma, const float* __restrict__ beta,
        const short* __restrict__ W0T, short* __restrict__ H) {
    __shared__ __align__(16) short a_lds[64][264];   // 256 + 8 pad
    __shared__ float psum[64][4];
    __shared__ float psq[64][4];
    __shared__ float mu_s[64];
    __shared__ float rs_s[64];

    const int tid = threadIdx.x;
    const int lane = tid & 63;
    const int w = tid >> 6;
    const int m0 = blockIdx.x * 64;

    // ---- stage x(state) fp32 -> bf16 LDS; 2 batches of 8 in-flight float4s
    #pragma unroll
    for (int half = 0; half < 2; ++half) {
        float4 v[8];
        #pragma unroll
        for (int c = 0; c < 8; ++c) {
            int s = (half * 8 + c) * 256 + tid;     // float4 slot, 64 rows x 64 slots
            int row = s >> 6;
            int k4 = (s & 63) << 2;
            v[c] = *reinterpret_cast<const float4*>(x + (size_t)(m0 + row) * XDIM + k4);
        }
        __builtin_amdgcn_sched_barrier(0);   // keep all 8 loads issued before any use
        #pragma unroll
        for (int c = 0; c < 8; ++c) {
            int s = (half * 8 + c) * 256 + tid;
            int row = s >> 6;
            int k4 = (s & 63) << 2;
            short4v sv;
            sv.x = f2b(v[c].x); sv.y = f2b(v[c].y); sv.z = f2b(v[c].z); sv.w = f2b(v[c].w);
            *reinterpret_cast<short4v*>(&a_lds[row][k4]) = sv;
        }
    }
    __syncthreads();

    const int q = lane >> 4;
    const int l15 = lane & 15;

    floatx4 acc[4][4] = {};                    // [mi][ni], rows mi*16+q*4+r, cols w*64+ni*16+l15
    const short* Bw = W0T + (size_t)(w << 6) * HID;

    for (int k0 = 0; k0 < 256; k0 += 32) {
        short8 af[4], bf[4];
        #pragma unroll
        for (int mi = 0; mi < 4; ++mi)
            af[mi] = *reinterpret_cast<const short8*>(&a_lds[mi * 16 + l15][k0 + q * 8]);
        #pragma unroll
        for (int ni = 0; ni < 4; ++ni)
            bf[ni] = *reinterpret_cast<const short8*>(Bw + (size_t)(ni * 16 + l15) * HID + k0 + q * 8);
        #pragma unroll
        for (int mi = 0; mi < 4; ++mi)
            #pragma unroll
            for (int ni = 0; ni < 4; ++ni)
                acc[mi][ni] = __builtin_amdgcn_mfma_f32_16x16x32_bf16(af[mi], bf[ni], acc[mi][ni], 0, 0, 0);
    }

    // ---- + b0, LN stats (shfl_xor over the 16 lanes sharing a row, then LDS cross-wave)
    float bias[4], gm[4], bt[4];
    #pragma unroll
    for (int ni = 0; ni < 4; ++ni) {
        int col = (w << 6) + ni * 16 + l15;
        bias[ni] = b0[col]; gm[ni] = gamma[col]; bt[ni] = beta[col];
    }
    #pragma unroll
    for (int mi = 0; mi < 4; ++mi) {
        #pragma unroll
        for (int r = 0; r < 4; ++r) {
            float s = 0.f, ss = 0.f;
            #pragma unroll
            for (int ni = 0; ni < 4; ++ni) {
                float v = acc[mi][ni][r] + bias[ni];
                acc[mi][ni][r] = v;
                s += v; ss += v * v;
            }
            #pragma unroll
            for (int off = 1; off < 16; off <<= 1) {
                s  += __shfl_xor(s,  off, 64);
                ss += __shfl_xor(ss, off, 64);
            }
            if (l15 == 0) {
                int row = mi * 16 + q * 4 + r;
                psum[row][w] = s;
                psq[row][w]  = ss;
            }
        }
    }
    __syncthreads();
    if (tid < 64) {
        float s  = psum[tid][0] + psum[tid][1] + psum[tid][2] + psum[tid][3];
        float ss = psq[tid][0]  + psq[tid][1]  + psq[tid][2]  + psq[tid][3];
        float mu = s * (1.f / 256.f);
        float var = ss * (1.f / 256.f) - mu * mu;
        mu_s[tid] = mu;
        rs_s[tid] = rsqrtf(var + 1e-5f);
    }
    __syncthreads();

    // ---- normalize + leaky + store bf16
    #pragma unroll
    for (int mi = 0; mi < 4; ++mi) {
        #pragma unroll
        for (int r = 0; r < 4; ++r) {
            int row = mi * 16 + q * 4 + r;
            float mu = mu_s[row], rs = rs_s[row];
            short* dst = H + (size_t)(m0 + row) * HID + (w << 6) + l15;
            #pragma unroll
            for (int ni = 0; ni < 4; ++ni) {
                float v = (acc[mi][ni][r] - mu) * rs * gm[ni] + bt[ni];
                v = (v >= 0.f) ? v : 0.1f * v;
                dst[ni * 16] = f2b(v);
            }
        }
    }
}

// ---------------------------------------------------------------------------
// K2: per (goal g, 64-row tile): t = relu(h @ W1[g] + b1[g]); out = t @ W2[g] + b2[g]
// H aliases out row-in-place (R2-proven race-free).  (unchanged)
// ---------------------------------------------------------------------------
__global__ __launch_bounds__(256, 2) void k2_heads(
        const short* H, const short* __restrict__ W1T, const short* __restrict__ W2T,
        const float* __restrict__ b1, const float* __restrict__ b2,
        const int* __restrict__ cursor, const int* __restrict__ perm,
        float* out) {
    const int g = blockIdx.y;
    const int t = blockIdx.x;
    const int cnt = cursor[g];
    if (t * 64 >= cnt) return;

    __shared__ __align__(16) short a_lds[64][264];
    __shared__ __align__(16) short t_lds[64][136];
    __shared__ int rows_s[64];

    const int tid = threadIdx.x;
    const int lane = tid & 63;
    const int w = tid >> 6;
    const int* pg = perm + (size_t)g * BATCH;

    if (tid < 64) {
        int idx = t * 64 + tid;
        rows_s[tid] = pg[idx < cnt ? idx : cnt - 1];
    }
    __syncthreads();

    // ---- gather h rows (bf16), coalesced 16B/lane
    #pragma unroll
    for (int c = 0; c < 8; ++c) {
        int s = c * 256 + tid;                 // short8 slot, 64 rows x 32 slots
        int row = s >> 5;
        int k8 = (s & 31) << 3;
        short8 v = *reinterpret_cast<const short8*>(H + (size_t)rows_s[row] * HID + k8);
        *reinterpret_cast<short8*>(&a_lds[row][k8]) = v;
    }
    __syncthreads();

    const int q = lane >> 4;
    const int l15 = lane & 15;

    // ---- GEMM1: 64x128, K=256; wave w owns cols [w*32, w*32+32)
    floatx4 acc1[4][2] = {};
    const short* B1 = W1T + (size_t)(g * HHID + (w << 5)) * HID;
    for (int k0 = 0; k0 < 256; k0 += 32) {
        short8 af[4], bf[2];
        #pragma unroll
        for (int mi = 0; mi < 4; ++mi)
            af[mi] = *reinterpret_cast<const short8*>(&a_lds[mi * 16 + l15][k0 + q * 8]);
        #pragma unroll
        for (int ni = 0; ni < 2; ++ni)
            bf[ni] = *reinterpret_cast<const short8*>(B1 + (size_t)(ni * 16 + l15) * HID + k0 + q * 8);
        #pragma unroll
        for (int mi = 0; mi < 4; ++mi)
            #pragma unroll
            for (int ni = 0; ni < 2; ++ni)
                acc1[mi][ni] = __builtin_amdgcn_mfma_f32_16x16x32_bf16(af[mi], bf[ni], acc1[mi][ni], 0, 0, 0);
    }
    // bias + relu -> t_lds (bf16)
    #pragma unroll
    for (int ni = 0; ni < 2; ++ni) {
        int col = (w << 5) + ni * 16 + l15;
        float bb = b1[g * HHID + col];
        #pragma unroll
        for (int mi = 0; mi < 4; ++mi)
            #pragma unroll
            for (int r = 0; r < 4; ++r) {
                int row = mi * 16 + q * 4 + r;
                float v = acc1[mi][ni][r] + bb;
                t_lds[row][col] = f2b(v > 0.f ? v : 0.f);
            }
    }
    __syncthreads();

    // ---- GEMM2: 64x128, K=128
    floatx4 acc2[4][2] = {};
    const short* B2 = W2T + (size_t)(g * ODIM + (w << 5)) * HHID;
    for (int k0 = 0; k0 < 128; k0 += 32) {
        short8 af[4], bf[2];
        #pragma unroll
        for (int mi = 0; mi < 4; ++mi)
            af[mi] = *reinterpret_cast<const short8*>(&t_lds[mi * 16 + l15][k0 + q * 8]);
        #pragma unroll
        for (int ni = 0; ni < 2; ++ni)
            bf[ni] = *reinterpret_cast<const short8*>(B2 + (size_t)(ni * 16 + l15) * HHID + k0 + q * 8);
        #pragma unroll
        for (int mi = 0; mi < 4; ++mi)
            #pragma unroll
            for (int ni = 0; ni < 2; ++ni)
                acc2[mi][ni] = __builtin_amdgcn_mfma_f32_16x16x32_bf16(af[mi], bf[ni], acc2[mi][ni], 0, 0, 0);
    }
    // bias + scatter out (fp32)
    #pragma unroll
    for (int ni = 0; ni < 2; ++ni) {
        int col = (w << 5) + ni * 16 + l15;
        float bb = b2[g * ODIM + col];
        #pragma unroll
        for (int mi = 0; mi < 4; ++mi)
            #pragma unroll
            for (int r = 0; r < 4; ++r) {
                int row = mi * 16 + q * 4 + r;
                int idx = t * 64 + row;
                if (idx < cnt)
                    out[(size_t)rows_s[row] * ODIM + col] = acc2[mi][ni][r] + bb;
            }
    }
}

// ---------------------------------------------------------------------------
// workspace layout (2.62 MB):
//   [0, 131072)            W0T bf16
//   [131072, 393216)       W1T bf16
//   [393216, 524288)       W2T bf16
//   [524288, 524304)       cursor (padded to 1024)
//   [525312, 2622464)      perm (4 x 131072 int)
// h (bf16, 64 MB) lives in d_out (same byte footprint as the fp32 output).
// ---------------------------------------------------------------------------
extern "C" void kernel_launch(void* const* d_in, const int* in_sizes, int n_in,
                              void* d_out, int out_size, void* d_ws, size_t ws_size,
                              hipStream_t stream) {
    const float* x     = (const float*)d_in[0];
    const float* W0    = (const float*)d_in[1];
    const float* b0    = (const float*)d_in[2];
    const float* gamma = (const float*)d_in[3];
    const float* beta  = (const float*)d_in[4];
    const float* W1    = (const float*)d_in[5];
    const float* b1    = (const float*)d_in[6];
    const float* W2    = (const float*)d_in[7];
    const float* b2    = (const float*)d_in[8];

    char* ws = (char*)d_ws;
    short* W0T  = (short*)(ws);
    short* W1T  = (short*)(ws + 131072);
    short* W2T  = (short*)(ws + 393216);
    int* cursor = (int*)(ws + 524288);
    int* perm   = (int*)(ws + 525312);
    short* H    = (short*)d_out;           // bf16 h aliases the fp32 output buffer
    float* out  = (float*)d_out;

    prep_kernel<<<512, 256, 0, stream>>>(W0, W1, W2, W0T, W1T, W2T, cursor);
    bucket_kernel<<<512, 256, 0, stream>>>(x, cursor, perm);
    k1_gemm_ln<<<BATCH / 64, 256, 0, stream>>>(x, b0, gamma, beta, W0T, H);
    k2_heads<<<dim3(BATCH / 64, 4), 256, 0, stream>>>(H, W1T, W2T, b1, b2, cursor, perm, out);
}